// Round 10
// baseline (989.032 us; speedup 1.0000x reference)
//
#include <hip/hip_runtime.h>
#include <hip/hip_bf16.h>
#include <stdint.h>

// Problem constants (fixed by reference)
#define H_K   2048
#define VV    128256
#define NROWS 1024
#define NCB   501            // vocab col-blocks of 256
#define SOFTCAP_F   30.0f
#define LS_EPS      0.1f
#define ZLOSS_SCALE 1e-4f
#define IGNORE_IDX  (-100)

typedef __attribute__((ext_vector_type(4)))  int   i32x4;
typedef __attribute__((ext_vector_type(8)))  int   i32x8;
typedef __attribute__((ext_vector_type(16))) float f32x16;

__device__ __forceinline__ void gload_lds16(const void* g, void* l) {
    __builtin_amdgcn_global_load_lds(
        (const __attribute__((address_space(1))) unsigned*)g,
        (__attribute__((address_space(3))) unsigned*)l, 16, 0, 0);
}

template <bool HI>
__device__ __forceinline__ unsigned pk8(float a, float b, unsigned old) {
    return (unsigned)__builtin_amdgcn_cvt_pk_fp8_f32(a, b, (int)old, HI);
}
// fragment = 32 fp8 k-bytes as two 16B slots 1024B apart (h-slot panel layout)
__device__ __forceinline__ i32x8 ldfrag(const char* p) {
    i32x4 lo = *(const i32x4*)p;
    i32x4 hi = *(const i32x4*)(p + 1024);
    return __builtin_shufflevector(lo, hi, 0, 1, 2, 3, 4, 5, 6, 7);
}

// ---- fp32 -> fp8 fragment-major panels (layout identical to R8/R9) ----
// panel (row>>5, k>>6) = 2048B: [h0 1024B][h1 1024B], slot byte = l*16,
// lane l = ((k32&1)<<5) | (row&31). Panel stream per row-group: 32 panels
// (64 KB), consecutive k. Coalesced-write thread map (R9-verified).
__device__ __forceinline__ void cvt_frag_row(const char* src, char* dst_base,
                                             int row, int k32) {
    unsigned d[8];
    #pragma unroll
    for (int i = 0; i < 8; ++i) {
        float4 v = *(const float4*)(src + i * 16);
        unsigned u = pk8<false>(v.x, v.y, 0u);
        d[i] = pk8<true>(v.z, v.w, u);
    }
    char* dst = dst_base + (size_t)((row >> 5) * 32 + (k32 >> 1)) * 2048
                         + ((((k32 & 1) << 5) | (row & 31))) * 16;
    uint4 u0; u0.x = d[0]; u0.y = d[1]; u0.z = d[2]; u0.w = d[3];
    uint4 u1; u1.x = d[4]; u1.y = d[5]; u1.z = d[6]; u1.w = d[7];
    *(uint4*)dst          = u0;    // k 0..15  (h=0)
    *(uint4*)(dst + 1024) = u1;    // k 16..31 (h=1)
}

__global__ void cvt_x_fp8(const float* __restrict__ x, char* __restrict__ xh) {
    const int g = blockIdx.x >> 3, q = blockIdx.x & 7;   // 32 row-groups x 8 slabs
    const int t = threadIdx.x;
    const int row = g * 32 + (t & 31);
    const int k32 = q * 8 + (t >> 5);
    cvt_frag_row((const char*)x + (size_t)row * 8192 + (size_t)k32 * 128,
                 xh, row, k32);
}

__global__ void cvt_w_fp8(const float* __restrict__ W, char* __restrict__ Wh,
                          int col0) {
    const int g = blockIdx.x >> 3, q = blockIdx.x & 7;
    const int t = threadIdx.x;
    const int row = g * 32 + (t & 31);                   // chunk-local col
    const int k32 = q * 8 + (t >> 5);
    cvt_frag_row((const char*)W + (size_t)(col0 + row) * 8192 + (size_t)k32 * 128,
                 Wh, row, k32);
}

// ---------------- fused GEMM + softcap + partial reductions ----------------
// 256x256 tile, 4 waves (2M x 2N), WAVE TILE 128x128: 16 MFMA 32x32x64 per
// iter per wave (~2200 SIMD-cyc of matrix work per sync phase). acc[4][4]
// f32x16 = 256 regs -> 1 wave/SIMD; MFMA block dominates phase overhead.
// One __syncthreads per iter: stage(j+1 -> buf^1) issued BEFORE the MFMA
// block, so the barrier's implicit vmcnt(0) drain is pre-landed.
__global__ __launch_bounds__(256, 1)
void gemm_fused(const char* __restrict__ Wh,    // chunk-local frag-major fp8
                const char* __restrict__ xh,
                const int* __restrict__ y,
                float* __restrict__ ws_se,
                float* __restrict__ ws_sl,
                float* __restrict__ ws_zy,
                int col_base, int nwg)          // nwg = 4*nb
{
    __shared__ char As[2][16384];   // 8 m-panels x 2KB, dbuf
    __shared__ char Bs[2][16384];   // 8 n-panels x 2KB, dbuf   (64 KB)

    const int tid  = threadIdx.x;
    const int lane = tid & 63;
    const int wid  = tid >> 6;          // 0..3
    const int wm   = wid >> 1;          // 0..1 -> 128 rows
    const int wn   = wid & 1;           // 0..1 -> 128 cols

    // bijective XCD swizzle (m204): q = nwg/8, r = nwg%8
    const int bid = blockIdx.x;
    const int xcd = bid & 7, o8 = bid >> 3;
    const int q8 = nwg >> 3, r8 = nwg & 7;
    const int work = (xcd < r8 ? xcd * (q8 + 1) : r8 * (q8 + 1) + (xcd - r8) * q8) + o8;
    const int mblk = work & 3;          // 4 m-sharers of a W col-tile adjacent
    const int nblk = work >> 2;
    const int row0 = mblk * 256;

    // staging sources: wave stages row-groups {2wid, 2wid+1} of A and
    // col-groups {2wid, 2wid+1} of B (4 KB each side per wave per iter)
    const char* aP0 = xh + (size_t)(mblk * 8 + 2 * wid) * 65536 + lane * 16;
    const char* aP1 = aP0 + 65536;
    const char* bP0 = Wh + (size_t)(nblk * 8 + 2 * wid) * 65536 + lane * 16;
    const char* bP1 = bP0 + 65536;

    // MFMA frag read offsets: A panel (4wm+mi), B panel (4wn+ni)
    const int aoff = (4 * wm) * 2048 + lane * 16;   // + mi*2048
    const int boff = (4 * wn) * 2048 + lane * 16;   // + ni*2048

    f32x16 acc[4][4] = {};

#define STAGE(J, BUF) do { \
    char* aD_ = (char*)As + (BUF) * 16384 + (2 * wid) * 2048; \
    char* bD_ = (char*)Bs + (BUF) * 16384 + (2 * wid) * 2048; \
    const size_t ko_ = (size_t)(J) * 2048; \
    gload_lds16(aP0 + ko_,        aD_);        gload_lds16(aP0 + ko_ + 1024, aD_ + 1024); \
    gload_lds16(aP1 + ko_,        aD_ + 2048); gload_lds16(aP1 + ko_ + 1024, aD_ + 3072); \
    gload_lds16(bP0 + ko_,        bD_);        gload_lds16(bP0 + ko_ + 1024, bD_ + 1024); \
    gload_lds16(bP1 + ko_,        bD_ + 2048); gload_lds16(bP1 + ko_ + 1024, bD_ + 3072); \
} while (0)

#define MFMS(D, AV, BV) D = __builtin_amdgcn_mfma_scale_f32_32x32x64_f8f6f4( \
                            AV, BV, D, 0, 0, 0, 127, 0, 127)

#define COMPUTE(BUF) do { \
    const char* Ab_ = (const char*)As + (BUF) * 16384; \
    const char* Bb_ = (const char*)Bs + (BUF) * 16384; \
    i32x8 b0_ = ldfrag(Bb_ + boff); \
    i32x8 b1_ = ldfrag(Bb_ + boff + 2048); \
    i32x8 b2_ = ldfrag(Bb_ + boff + 4096); \
    i32x8 b3_ = ldfrag(Bb_ + boff + 6144); \
    i32x8 a0_ = ldfrag(Ab_ + aoff); \
    i32x8 a1_ = ldfrag(Ab_ + aoff + 2048); \
    i32x8 a2_ = ldfrag(Ab_ + aoff + 4096); \
    i32x8 a3_ = ldfrag(Ab_ + aoff + 6144); \
    MFMS(acc[0][0], a0_, b0_); MFMS(acc[0][1], a0_, b1_); \
    MFMS(acc[0][2], a0_, b2_); MFMS(acc[0][3], a0_, b3_); \
    MFMS(acc[1][0], a1_, b0_); MFMS(acc[1][1], a1_, b1_); \
    MFMS(acc[1][2], a1_, b2_); MFMS(acc[1][3], a1_, b3_); \
    MFMS(acc[2][0], a2_, b0_); MFMS(acc[2][1], a2_, b1_); \
    MFMS(acc[2][2], a2_, b2_); MFMS(acc[2][3], a2_, b3_); \
    MFMS(acc[3][0], a3_, b0_); MFMS(acc[3][1], a3_, b1_); \
    MFMS(acc[3][2], a3_, b2_); MFMS(acc[3][3], a3_, b3_); \
} while (0)

    // prologue: stage K-chunk 0
    STAGE(0, 0);
    __syncthreads();

    #pragma unroll 1
    for (int j = 0; j < 31; ++j) {
        const int cur = j & 1;
        STAGE(j + 1, cur ^ 1);      // issue DMA first: lands under the MFMA block
        COMPUTE(cur);
        __syncthreads();            // implicit vmcnt(0)+lgkm(0): DMAs pre-landed
    }
    COMPUTE(1);                     // j = 31

    // ---- epilogue: softcap, z_y scatter, per-row partial sumexp/sumlogit ----
    // 32x32 C/D (R7/R8-verified): col = lane&31, row = (e&3)+8*(e>>2)+4*(lane>>5)
    #pragma unroll
    for (int mi = 0; mi < 4; ++mi)
        #pragma unroll
        for (int ni = 0; ni < 4; ++ni)
            #pragma unroll
            for (int e = 0; e < 16; ++e) {
                float v  = acc[mi][ni][e];
                float ex = __expf(v * (1.0f / 15.0f));            // e^{2v/30}
                acc[mi][ni][e] = SOFTCAP_F - 60.0f / (ex + 1.0f); // 30*tanh(v/30)
            }

    const int h  = lane >> 5;
    const int cl = lane & 31;
    const int wcb = col_base + nblk * 256 + wn * 128;   // wave col base
    #pragma unroll
    for (int mi = 0; mi < 4; ++mi) {
        #pragma unroll
        for (int e = 0; e < 16; ++e) {
            const int rit  = (e & 3) + ((e >> 2) << 3) + (h << 2);
            const int grow = row0 + wm * 128 + mi * 32 + rit;
            int ty = y[grow];
            int tc = ty - wcb;
            if ((unsigned)tc < 128u && (tc & 31) == cl) {
                const int nt = tc >> 5;
                float zv = (nt == 0) ? acc[mi][0][e] :
                           (nt == 1) ? acc[mi][1][e] :
                           (nt == 2) ? acc[mi][2][e] : acc[mi][3][e];
                ws_zy[grow] = zv;
            }
            float sl_ = 0.f, se_ = 0.f;
            #pragma unroll
            for (int ni = 0; ni < 4; ++ni) {
                float v = acc[mi][ni][e];
                sl_ += v;
                se_ += __expf(v);   // |logits| <= 30 -> no max-shift needed
            }
            #pragma unroll
            for (int d = 1; d < 32; d <<= 1) {
                se_ += __shfl_xor(se_, d, 64);
                sl_ += __shfl_xor(sl_, d, 64);
            }
            if (cl == 0) {
                atomicAdd(&ws_se[grow], se_);
                atomicAdd(&ws_sl[grow], sl_);
            }
        }
    }
}

// ---------------- finalize: per-token loss + mean ----------------
__global__ void finalize_kernel(const float* __restrict__ ws_se,
                                const float* __restrict__ ws_sl,
                                const float* __restrict__ ws_zy,
                                const int* __restrict__ y,
                                float* __restrict__ out, int n)
{
    __shared__ float sL[16], sC[16];
    const int tid = threadIdx.x;
    float loss = 0.f, cnt = 0.f;
    if (tid < n) {
        int ty = y[tid];
        if (ty != IGNORE_IDX) {
            float lse = logf(ws_se[tid]);
            float ce  = lse - (1.0f - LS_EPS) * ws_zy[tid]
                          - (LS_EPS / (float)VV) * ws_sl[tid];
            loss = ce + ZLOSS_SCALE * lse * lse;
            cnt  = 1.f;
        }
    }
    #pragma unroll
    for (int d = 32; d >= 1; d >>= 1) {
        loss += __shfl_down(loss, d, 64);
        cnt  += __shfl_down(cnt,  d, 64);
    }
    const int w = tid >> 6;
    if ((tid & 63) == 0) { sL[w] = loss; sC[w] = cnt; }
    __syncthreads();
    if (tid == 0) {
        float L = 0.f, C = 0.f;
        #pragma unroll
        for (int i = 0; i < 16; ++i) { L += sL[i]; C += sC[i]; }
        out[0] = L / fmaxf(C, 1.0f);
    }
}

extern "C" void kernel_launch(void* const* d_in, const int* in_sizes, int n_in,
                              void* d_out, int out_size, void* d_ws, size_t ws_size,
                              hipStream_t stream) {
    const float* x = (const float*)d_in[0];
    const float* W = (const float*)d_in[1];
    const int*   y = (const int*)d_in[2];
    float* out = (float*)d_out;

    char*  ws    = (char*)d_ws;
    float* ws_se = (float*)(ws);              // [1024] sumexp
    float* ws_sl = (float*)(ws + 4096);       // [1024] sumlogit
    float* ws_zy = (float*)(ws + 8192);       // [1024] target logit
    char*  xh    = ws + 16384;                // 2 MB fp8 x, frag-major
    char*  Wh    = ws + 16384 + 2097152;      // fp8 W chunk, frag-major

    // chunk vocab by available ws (deterministic: ws_size fixed per run)
    const size_t fixed = 16384 + 2097152;
    const size_t avail = ws_size > fixed ? ws_size - fixed : 0;
    int nbc = (int)(avail / 524288);          // 512 KB per 256-col block
    if (nbc > NCB) nbc = NCB;
    if (nbc < 1)   nbc = 1;

    (void)hipMemsetAsync(ws, 0, 12288, stream);
    cvt_x_fp8<<<256, 256, 0, stream>>>(x, xh);

    for (int c0 = 0; c0 < NCB; c0 += nbc) {
        const int nb = (NCB - c0 < nbc) ? (NCB - c0) : nbc;
        cvt_w_fp8<<<nb * 64, 256, 0, stream>>>(W, Wh, c0 * 256);
        gemm_fused<<<nb * 4, 256, 0, stream>>>(Wh, xh, y, ws_se, ws_sl, ws_zy,
                                               c0 * 256, nb * 4);
    }

    finalize_kernel<<<1, 1024, 0, stream>>>(ws_se, ws_sl, ws_zy, y, out, NROWS);
}

// Round 11
// 911.694 us; speedup vs baseline: 1.0848x; 1.0848x over previous
//
#include <hip/hip_runtime.h>
#include <hip/hip_bf16.h>
#include <stdint.h>

// Problem constants (fixed by reference)
#define H_K   2048
#define VV    128256
#define NROWS 1024
#define NCB   501            // vocab col-blocks of 256
#define SOFTCAP_F   30.0f
#define LS_EPS      0.1f
#define ZLOSS_SCALE 1e-4f
#define IGNORE_IDX  (-100)

typedef __attribute__((ext_vector_type(4)))  int   i32x4;
typedef __attribute__((ext_vector_type(8)))  int   i32x8;
typedef __attribute__((ext_vector_type(16))) float f32x16;

__device__ __forceinline__ void gload_lds16(const void* g, void* l) {
    __builtin_amdgcn_global_load_lds(
        (const __attribute__((address_space(1))) unsigned*)g,
        (__attribute__((address_space(3))) unsigned*)l, 16, 0, 0);
}
#define WAITVM(N) asm volatile("s_waitcnt vmcnt(" #N ")" ::: "memory")
#define WAITLG_SB do { asm volatile("s_waitcnt lgkmcnt(0)" ::: "memory"); \
                       __builtin_amdgcn_sched_barrier(0); } while (0)

template <bool HI>
__device__ __forceinline__ unsigned pk8(float a, float b, unsigned old) {
    return (unsigned)__builtin_amdgcn_cvt_pk_fp8_f32(a, b, (int)old, HI);
}
// fragment = 32 fp8 k-bytes as two 16B slots 1024B apart (h-slot panel layout)
__device__ __forceinline__ i32x8 ldfrag(const char* p) {
    i32x4 lo = *(const i32x4*)p;
    i32x4 hi = *(const i32x4*)(p + 1024);
    return __builtin_shufflevector(lo, hi, 0, 1, 2, 3, 4, 5, 6, 7);
}

// ---- fp32 -> fp8 fragment-major panels (layout identical to R8-R10) ----
// panel (row>>5, k>>6) = 2048B: [h0 1024B][h1 1024B], slot byte = l*16,
// lane l = ((k32&1)<<5) | (row&31). Coalesced-write thread map (R9-verified).
__device__ __forceinline__ void cvt_frag_row(const char* src, char* dst_base,
                                             int row, int k32) {
    unsigned d[8];
    #pragma unroll
    for (int i = 0; i < 8; ++i) {
        float4 v = *(const float4*)(src + i * 16);
        unsigned u = pk8<false>(v.x, v.y, 0u);
        d[i] = pk8<true>(v.z, v.w, u);
    }
    char* dst = dst_base + (size_t)((row >> 5) * 32 + (k32 >> 1)) * 2048
                         + ((((k32 & 1) << 5) | (row & 31))) * 16;
    uint4 u0; u0.x = d[0]; u0.y = d[1]; u0.z = d[2]; u0.w = d[3];
    uint4 u1; u1.x = d[4]; u1.y = d[5]; u1.z = d[6]; u1.w = d[7];
    *(uint4*)dst          = u0;    // k 0..15  (h=0)
    *(uint4*)(dst + 1024) = u1;    // k 16..31 (h=1)
}

__global__ void cvt_x_fp8(const float* __restrict__ x, char* __restrict__ xh) {
    const int g = blockIdx.x >> 3, q = blockIdx.x & 7;
    const int t = threadIdx.x;
    const int row = g * 32 + (t & 31);
    const int k32 = q * 8 + (t >> 5);
    cvt_frag_row((const char*)x + (size_t)row * 8192 + (size_t)k32 * 128,
                 xh, row, k32);
}

__global__ void cvt_w_fp8(const float* __restrict__ W, char* __restrict__ Wh,
                          int col0) {
    const int g = blockIdx.x >> 3, q = blockIdx.x & 7;
    const int t = threadIdx.x;
    const int row = g * 32 + (t & 31);                   // chunk-local col
    const int k32 = q * 8 + (t >> 5);
    cvt_frag_row((const char*)W + (size_t)(col0 + row) * 8192 + (size_t)k32 * 128,
                 Wh, row, k32);
}

// ---------------- fused GEMM + softcap + partial reductions ----------------
// m201-style 8-phase port, fp8 32x32x64. 512 thr / 8 waves (2M x 4N), tile
// 256x256, wave 128x64, acc[4][2] (128 AGPR) -> 2 waves/SIMD. LDS: 4-slot
// chunk ring x 32KB ([A 16K][B 16K]) = 128 KB, 1 block/CU.
// 64 phases: pair c = {read chunk c | stage chunk c+3 half | vmcnt(8) |
// barrier | lgkm0 | setprio 4 MFMA | barrier} x2. Ledger: chunk c's 4 loads
// (issued pair c-3) drained exactly by pair c-1's odd vmcnt(8). Tail peels
// {8,4},{4,0},{0,0}. Loads never drained to 0 mid-loop (T3+T4).
__global__ __launch_bounds__(512, 2)
void gemm_fused(const char* __restrict__ Wh,    // chunk-local frag-major fp8
                const char* __restrict__ xh,
                const int* __restrict__ y,
                float* __restrict__ ws_se,
                float* __restrict__ ws_sl,
                float* __restrict__ ws_zy,
                int col_base, int nwg)          // nwg = 4*nb
{
    __shared__ char Ls[4][32768];   // slot: [A 8 panels x 2KB][B 8 panels x 2KB]

    const int tid  = threadIdx.x;
    const int lane = tid & 63;
    const int wid  = tid >> 6;          // 0..7
    const int wm   = wid >> 2;          // 0..1 -> 128 rows
    const int wn   = wid & 3;           // 0..3 -> 64 cols

    // bijective XCD swizzle (m204)
    const int bid = blockIdx.x;
    const int xcd = bid & 7, o8 = bid >> 3;
    const int q8 = nwg >> 3, r8 = nwg & 7;
    const int work = (xcd < r8 ? xcd * (q8 + 1) : r8 * (q8 + 1) + (xcd - r8) * q8) + o8;
    const int mblk = work & 3;          // 4 m-sharers of a W col-tile adjacent
    const int nblk = work >> 2;
    const int row0 = mblk * 256;

    // staging: wave w owns A row-group w and B col-group w (2 gloads each)
    const char* aP = xh + (size_t)(mblk * 8 + wid) * 65536 + lane * 16;
    const char* bP = Wh + (size_t)(nblk * 8 + wid) * 65536 + lane * 16;

    // MFMA frag read offsets within a slot
    const int aoff = (wm * 4) * 2048 + lane * 16;           // + mi*2048
    const int boff = 16384 + (wn * 2) * 2048 + lane * 16;   // + ni*2048

    f32x16 acc[4][2] = {};

    // ---- prologue: stage chunks 0,1,2 (12 gloads/wave); drain chunk 0 ----
    #pragma unroll
    for (int c = 0; c < 3; ++c) {
        char* D = (char*)Ls + c * 32768;
        gload_lds16(aP + (size_t)c * 2048,        D + wid * 2048);
        gload_lds16(aP + (size_t)c * 2048 + 1024, D + wid * 2048 + 1024);
        gload_lds16(bP + (size_t)c * 2048,        D + 16384 + wid * 2048);
        gload_lds16(bP + (size_t)c * 2048 + 1024, D + 16384 + wid * 2048 + 1024);
    }
    WAITVM(8);
    __builtin_amdgcn_s_barrier();

#define MFMS(D, AV, BV) D = __builtin_amdgcn_mfma_scale_f32_32x32x64_f8f6f4( \
                            AV, BV, D, 0, 0, 0, 127, 0, 127)

#define PAIR(C, STG, VA, VB) do { \
    const char* S_ = (const char*)Ls + ((C) & 3) * 32768; \
    char* D_ = (char*)Ls + (((C) + 3) & 3) * 32768; \
    const size_t ko_ = (size_t)((C) + 3) * 2048; \
    /* ---- even phase: B0,B1 + A0,A1 ; stage A-half(c+3) ---- */ \
    i32x8 b0_ = ldfrag(S_ + boff); \
    i32x8 b1_ = ldfrag(S_ + boff + 2048); \
    i32x8 a0_ = ldfrag(S_ + aoff); \
    i32x8 a1_ = ldfrag(S_ + aoff + 2048); \
    if (STG) { \
        gload_lds16(aP + ko_,        D_ + wid * 2048); \
        gload_lds16(aP + ko_ + 1024, D_ + wid * 2048 + 1024); \
    } \
    WAITVM(VA); \
    __builtin_amdgcn_s_barrier(); \
    WAITLG_SB; \
    __builtin_amdgcn_s_setprio(1); \
    MFMS(acc[0][0], a0_, b0_); MFMS(acc[0][1], a0_, b1_); \
    MFMS(acc[1][0], a1_, b0_); MFMS(acc[1][1], a1_, b1_); \
    __builtin_amdgcn_s_setprio(0); \
    __builtin_amdgcn_s_barrier(); \
    /* ---- odd phase: A2,A3 ; stage B-half(c+3) ---- */ \
    a0_ = ldfrag(S_ + aoff + 4096); \
    a1_ = ldfrag(S_ + aoff + 6144); \
    if (STG) { \
        gload_lds16(bP + ko_,        D_ + 16384 + wid * 2048); \
        gload_lds16(bP + ko_ + 1024, D_ + 16384 + wid * 2048 + 1024); \
    } \
    WAITVM(VB); \
    __builtin_amdgcn_s_barrier(); \
    WAITLG_SB; \
    __builtin_amdgcn_s_setprio(1); \
    MFMS(acc[2][0], a0_, b0_); MFMS(acc[2][1], a0_, b1_); \
    MFMS(acc[3][0], a1_, b0_); MFMS(acc[3][1], a1_, b1_); \
    __builtin_amdgcn_s_setprio(0); \
    __builtin_amdgcn_s_barrier(); \
} while (0)

    #pragma unroll 1
    for (int c = 0; c < 29; ++c)
        PAIR(c, 1, 8, 8);
    PAIR(29, 0, 8, 4);
    PAIR(30, 0, 4, 0);
    PAIR(31, 0, 0, 0);

    // ---- epilogue: softcap, z_y scatter, per-row partial sumexp/sumlogit ----
    // 32x32 C/D (R7/R8-verified): col = lane&31, row = (e&3)+8*(e>>2)+4*(lane>>5)
    #pragma unroll
    for (int mi = 0; mi < 4; ++mi)
        #pragma unroll
        for (int ni = 0; ni < 2; ++ni)
            #pragma unroll
            for (int e = 0; e < 16; ++e) {
                float v  = acc[mi][ni][e];
                float ex = __expf(v * (1.0f / 15.0f));            // e^{2v/30}
                acc[mi][ni][e] = SOFTCAP_F - 60.0f / (ex + 1.0f); // 30*tanh(v/30)
            }

    const int h  = lane >> 5;
    const int cl = lane & 31;
    const int cbase = col_base + nblk * 256 + wn * 64;
    #pragma unroll
    for (int mi = 0; mi < 4; ++mi) {
        #pragma unroll
        for (int e = 0; e < 16; ++e) {
            const int rit  = (e & 3) + ((e >> 2) << 3) + (h << 2);
            const int grow = row0 + wm * 128 + mi * 32 + rit;
            int ty = y[grow];
            int tc = ty - cbase;
            if ((unsigned)tc < 64u && (tc & 31) == cl)
                ws_zy[grow] = (tc >> 5) ? acc[mi][1][e] : acc[mi][0][e];
            float v0 = acc[mi][0][e], v1 = acc[mi][1][e];
            float sl_ = v0 + v1;
            float se_ = __expf(v0) + __expf(v1);   // |logits|<=30, no max-shift
            #pragma unroll
            for (int d = 1; d < 32; d <<= 1) {
                se_ += __shfl_xor(se_, d, 64);
                sl_ += __shfl_xor(sl_, d, 64);
            }
            if (cl == 0) {
                atomicAdd(&ws_se[grow], se_);
                atomicAdd(&ws_sl[grow], sl_);
            }
        }
    }
}

// ---------------- finalize: per-token loss + mean ----------------
__global__ void finalize_kernel(const float* __restrict__ ws_se,
                                const float* __restrict__ ws_sl,
                                const float* __restrict__ ws_zy,
                                const int* __restrict__ y,
                                float* __restrict__ out, int n)
{
    __shared__ float sL[16], sC[16];
    const int tid = threadIdx.x;
    float loss = 0.f, cnt = 0.f;
    if (tid < n) {
        int ty = y[tid];
        if (ty != IGNORE_IDX) {
            float lse = logf(ws_se[tid]);
            float ce  = lse - (1.0f - LS_EPS) * ws_zy[tid]
                          - (LS_EPS / (float)VV) * ws_sl[tid];
            loss = ce + ZLOSS_SCALE * lse * lse;
            cnt  = 1.f;
        }
    }
    #pragma unroll
    for (int d = 32; d >= 1; d >>= 1) {
        loss += __shfl_down(loss, d, 64);
        cnt  += __shfl_down(cnt,  d, 64);
    }
    const int w = tid >> 6;
    if ((tid & 63) == 0) { sL[w] = loss; sC[w] = cnt; }
    __syncthreads();
    if (tid == 0) {
        float L = 0.f, C = 0.f;
        #pragma unroll
        for (int i = 0; i < 16; ++i) { L += sL[i]; C += sC[i]; }
        out[0] = L / fmaxf(C, 1.0f);
    }
}

extern "C" void kernel_launch(void* const* d_in, const int* in_sizes, int n_in,
                              void* d_out, int out_size, void* d_ws, size_t ws_size,
                              hipStream_t stream) {
    const float* x = (const float*)d_in[0];
    const float* W = (const float*)d_in[1];
    const int*   y = (const int*)d_in[2];
    float* out = (float*)d_out;

    char*  ws    = (char*)d_ws;
    float* ws_se = (float*)(ws);              // [1024] sumexp
    float* ws_sl = (float*)(ws + 4096);       // [1024] sumlogit
    float* ws_zy = (float*)(ws + 8192);       // [1024] target logit
    char*  xh    = ws + 16384;                // 2 MB fp8 x, frag-major
    char*  Wh    = ws + 16384 + 2097152;      // fp8 W chunk, frag-major

    // chunk vocab by available ws (deterministic: ws_size fixed per run)
    const size_t fixed = 16384 + 2097152;
    const size_t avail = ws_size > fixed ? ws_size - fixed : 0;
    int nbc = (int)(avail / 524288);          // 512 KB per 256-col block
    if (nbc > NCB) nbc = NCB;
    if (nbc < 1)   nbc = 1;

    (void)hipMemsetAsync(ws, 0, 12288, stream);
    cvt_x_fp8<<<256, 256, 0, stream>>>(x, xh);

    for (int c0 = 0; c0 < NCB; c0 += nbc) {
        const int nb = (NCB - c0 < nbc) ? (NCB - c0) : nbc;
        cvt_w_fp8<<<nb * 64, 256, 0, stream>>>(W, Wh, c0 * 256);
        gemm_fused<<<nb * 4, 512, 0, stream>>>(Wh, xh, y, ws_se, ws_sl, ws_zy,
                                               c0 * 256, nb * 4);
    }

    finalize_kernel<<<1, 1024, 0, stream>>>(ws_se, ws_sl, ws_zy, y, out, NROWS);
}

// Round 12
// 774.697 us; speedup vs baseline: 1.2767x; 1.1768x over previous
//
#include <hip/hip_runtime.h>
#include <hip/hip_bf16.h>
#include <stdint.h>

// Problem constants (fixed by reference)
#define H_K   2048
#define VV    128256
#define NROWS 1024
#define NCB   501            // vocab col-blocks of 256 (chunk unit)
#define SOFTCAP_F   30.0f
#define LS_EPS      0.1f
#define ZLOSS_SCALE 1e-4f
#define IGNORE_IDX  (-100)

typedef __attribute__((ext_vector_type(4)))  int   i32x4;
typedef __attribute__((ext_vector_type(8)))  int   i32x8;
typedef __attribute__((ext_vector_type(16))) float f32x16;

__device__ __forceinline__ void gload_lds16(const void* g, void* l) {
    __builtin_amdgcn_global_load_lds(
        (const __attribute__((address_space(1))) unsigned*)g,
        (__attribute__((address_space(3))) unsigned*)l, 16, 0, 0);
}

template <bool HI>
__device__ __forceinline__ unsigned pk8(float a, float b, unsigned old) {
    return (unsigned)__builtin_amdgcn_cvt_pk_fp8_f32(a, b, (int)old, HI);
}
// fragment = 32 fp8 k-bytes as two 16B slots 1024B apart (h-slot panel layout)
__device__ __forceinline__ i32x8 ldfrag(const char* p) {
    i32x4 lo = *(const i32x4*)p;
    i32x4 hi = *(const i32x4*)(p + 1024);
    return __builtin_shufflevector(lo, hi, 0, 1, 2, 3, 4, 5, 6, 7);
}

// ---- fp32 -> fp8 fragment-major panels (layout identical to R8-R11) ----
// panel (row>>5, k>>6) = 2048B: [h0 1024B][h1 1024B], slot byte = l*16,
// lane l = ((k32&1)<<5) | (row&31). Coalesced-write thread map (R9-verified).
__device__ __forceinline__ void cvt_frag_row(const char* src, char* dst_base,
                                             int row, int k32) {
    unsigned d[8];
    #pragma unroll
    for (int i = 0; i < 8; ++i) {
        float4 v = *(const float4*)(src + i * 16);
        unsigned u = pk8<false>(v.x, v.y, 0u);
        d[i] = pk8<true>(v.z, v.w, u);
    }
    char* dst = dst_base + (size_t)((row >> 5) * 32 + (k32 >> 1)) * 2048
                         + ((((k32 & 1) << 5) | (row & 31))) * 16;
    uint4 u0; u0.x = d[0]; u0.y = d[1]; u0.z = d[2]; u0.w = d[3];
    uint4 u1; u1.x = d[4]; u1.y = d[5]; u1.z = d[6]; u1.w = d[7];
    *(uint4*)dst          = u0;    // k 0..15  (h=0)
    *(uint4*)(dst + 1024) = u1;    // k 16..31 (h=1)
}

__global__ void cvt_x_fp8(const float* __restrict__ x, char* __restrict__ xh) {
    const int g = blockIdx.x >> 3, q = blockIdx.x & 7;
    const int t = threadIdx.x;
    const int row = g * 32 + (t & 31);
    const int k32 = q * 8 + (t >> 5);
    cvt_frag_row((const char*)x + (size_t)row * 8192 + (size_t)k32 * 128,
                 xh, row, k32);
}

__global__ void cvt_w_fp8(const float* __restrict__ W, char* __restrict__ Wh,
                          int col0) {
    const int g = blockIdx.x >> 3, q = blockIdx.x & 7;
    const int t = threadIdx.x;
    const int row = g * 32 + (t & 31);                   // chunk-local col
    const int k32 = q * 8 + (t >> 5);
    cvt_frag_row((const char*)W + (size_t)(col0 + row) * 8192 + (size_t)k32 * 128,
                 Wh, row, k32);
}

// ---------------- fused GEMM + softcap + partial reductions ----------------
// m97/m148-faithful structure: 128x128 tile, 256 thr / 4 waves (2M x 2N),
// wave 64x64, acc[2][2] f32x16 (64 acc regs). LDS 2 x 16KB = 32 KB only ->
// 3 blocks/CU co-resident; barrier drains hidden by CROSS-BLOCK overlap
// (m114/m97), not in-loop vmcnt. Loop: {issue 4 gload_lds(j+1) | 8 ds_read |
// 4 MFMA | __syncthreads}.
__global__ __launch_bounds__(256, 3)
void gemm_fused(const char* __restrict__ Wh,    // chunk-local frag-major fp8
                const char* __restrict__ xh,
                const int* __restrict__ y,
                float* __restrict__ ws_se,
                float* __restrict__ ws_sl,
                float* __restrict__ ws_zy,
                int col_base, int qx)           // qx = works per XCD = 2*nb
{
    __shared__ char Ls[2][16384];   // [A: 4 panels x 2KB][B: 4 panels x 2KB]

    const int tid  = threadIdx.x;
    const int lane = tid & 63;
    const int wid  = tid >> 6;          // 0..3
    const int wm   = wid >> 1;          // 0..1 -> 64 rows
    const int wn   = wid & 1;           // 0..1 -> 64 cols

    // XCD-grouped work order: grid = 8*qx; 8 m-sharers consecutive per XCD
    const int bid  = blockIdx.x;
    const int work = (bid & 7) * qx + (bid >> 3);
    const int mblk = work & 7;          // 8 m-blocks share each W col-tile
    const int nblk = work >> 3;         // chunk-local 128-col block
    const int row0 = mblk * 128;

    // staging: wave w stages A panel w and B panel w (2 gloads each)
    const char* aP = xh + (size_t)(mblk * 4 + wid) * 65536 + lane * 16;
    const char* bP = Wh + (size_t)(nblk * 4 + wid) * 65536 + lane * 16;

    // MFMA frag read offsets within a buffer
    const int aoff = (wm * 2) * 2048 + lane * 16;          // + mi*2048
    const int boff = 8192 + (wn * 2) * 2048 + lane * 16;   // + ni*2048

    f32x16 acc[2][2] = {};

#define STAGE(J, BUF) do { \
    char* D_ = (char*)Ls + (BUF) * 16384; \
    const size_t ko_ = (size_t)(J) * 2048; \
    gload_lds16(aP + ko_,        D_ + wid * 2048); \
    gload_lds16(aP + ko_ + 1024, D_ + wid * 2048 + 1024); \
    gload_lds16(bP + ko_,        D_ + 8192 + wid * 2048); \
    gload_lds16(bP + ko_ + 1024, D_ + 8192 + wid * 2048 + 1024); \
} while (0)

#define MFMS(D, AV, BV) D = __builtin_amdgcn_mfma_scale_f32_32x32x64_f8f6f4( \
                            AV, BV, D, 0, 0, 0, 127, 0, 127)

#define COMPUTE(BUF) do { \
    const char* P_ = (const char*)Ls + (BUF) * 16384; \
    i32x8 a0_ = ldfrag(P_ + aoff); \
    i32x8 a1_ = ldfrag(P_ + aoff + 2048); \
    i32x8 b0_ = ldfrag(P_ + boff); \
    i32x8 b1_ = ldfrag(P_ + boff + 2048); \
    MFMS(acc[0][0], a0_, b0_); MFMS(acc[0][1], a0_, b1_); \
    MFMS(acc[1][0], a1_, b0_); MFMS(acc[1][1], a1_, b1_); \
} while (0)

    // prologue
    STAGE(0, 0);
    __syncthreads();

    #pragma unroll 1
    for (int j = 0; j < 31; ++j) {
        const int cur = j & 1;
        STAGE(j + 1, cur ^ 1);      // issue next-tile DMA first
        COMPUTE(cur);
        __syncthreads();            // implicit vmcnt0: cross-block overlap hides it
    }
    COMPUTE(1);                     // j = 31

    // ---- epilogue: softcap, z_y scatter, per-row partial sumexp/sumlogit ----
    // 32x32 C/D (R7-R11 verified): col = lane&31, row = (e&3)+8*(e>>2)+4*(lane>>5)
    #pragma unroll
    for (int mi = 0; mi < 2; ++mi)
        #pragma unroll
        for (int ni = 0; ni < 2; ++ni)
            #pragma unroll
            for (int e = 0; e < 16; ++e) {
                float v  = acc[mi][ni][e];
                float ex = __expf(v * (1.0f / 15.0f));            // e^{2v/30}
                acc[mi][ni][e] = SOFTCAP_F - 60.0f / (ex + 1.0f); // 30*tanh(v/30)
            }

    const int h  = lane >> 5;
    const int cl = lane & 31;
    const int cbase = col_base + nblk * 128 + wn * 64;
    #pragma unroll
    for (int mi = 0; mi < 2; ++mi) {
        #pragma unroll
        for (int e = 0; e < 16; ++e) {
            const int rit  = (e & 3) + ((e >> 2) << 3) + (h << 2);
            const int grow = row0 + wm * 64 + mi * 32 + rit;
            int ty = y[grow];
            int tc = ty - cbase;
            if ((unsigned)tc < 64u && (tc & 31) == cl)
                ws_zy[grow] = (tc >> 5) ? acc[mi][1][e] : acc[mi][0][e];
            float v0 = acc[mi][0][e], v1 = acc[mi][1][e];
            float sl_ = v0 + v1;
            float se_ = __expf(v0) + __expf(v1);   // |logits|<=30, no max-shift
            #pragma unroll
            for (int d = 1; d < 32; d <<= 1) {
                se_ += __shfl_xor(se_, d, 64);
                sl_ += __shfl_xor(sl_, d, 64);
            }
            if (cl == 0) {
                atomicAdd(&ws_se[grow], se_);
                atomicAdd(&ws_sl[grow], sl_);
            }
        }
    }
}

// ---------------- finalize: per-token loss + mean ----------------
__global__ void finalize_kernel(const float* __restrict__ ws_se,
                                const float* __restrict__ ws_sl,
                                const float* __restrict__ ws_zy,
                                const int* __restrict__ y,
                                float* __restrict__ out, int n)
{
    __shared__ float sL[16], sC[16];
    const int tid = threadIdx.x;
    float loss = 0.f, cnt = 0.f;
    if (tid < n) {
        int ty = y[tid];
        if (ty != IGNORE_IDX) {
            float lse = logf(ws_se[tid]);
            float ce  = lse - (1.0f - LS_EPS) * ws_zy[tid]
                          - (LS_EPS / (float)VV) * ws_sl[tid];
            loss = ce + ZLOSS_SCALE * lse * lse;
            cnt  = 1.f;
        }
    }
    #pragma unroll
    for (int d = 32; d >= 1; d >>= 1) {
        loss += __shfl_down(loss, d, 64);
        cnt  += __shfl_down(cnt,  d, 64);
    }
    const int w = tid >> 6;
    if ((tid & 63) == 0) { sL[w] = loss; sC[w] = cnt; }
    __syncthreads();
    if (tid == 0) {
        float L = 0.f, C = 0.f;
        #pragma unroll
        for (int i = 0; i < 16; ++i) { L += sL[i]; C += sC[i]; }
        out[0] = L / fmaxf(C, 1.0f);
    }
}

extern "C" void kernel_launch(void* const* d_in, const int* in_sizes, int n_in,
                              void* d_out, int out_size, void* d_ws, size_t ws_size,
                              hipStream_t stream) {
    const float* x = (const float*)d_in[0];
    const float* W = (const float*)d_in[1];
    const int*   y = (const int*)d_in[2];
    float* out = (float*)d_out;

    char*  ws    = (char*)d_ws;
    float* ws_se = (float*)(ws);              // [1024] sumexp
    float* ws_sl = (float*)(ws + 4096);       // [1024] sumlogit
    float* ws_zy = (float*)(ws + 8192);       // [1024] target logit
    char*  xh    = ws + 16384;                // 2 MB fp8 x, frag-major
    char*  Wh    = ws + 16384 + 2097152;      // fp8 W chunk, frag-major

    // chunk vocab by available ws (deterministic: ws_size fixed per run)
    const size_t fixed = 16384 + 2097152;
    const size_t avail = ws_size > fixed ? ws_size - fixed : 0;
    int nbc = (int)(avail / 524288);          // 512 KB per 256-col unit
    if (nbc > NCB) nbc = NCB;
    if (nbc < 1)   nbc = 1;

    (void)hipMemsetAsync(ws, 0, 12288, stream);
    cvt_x_fp8<<<256, 256, 0, stream>>>(x, xh);

    for (int c0 = 0; c0 < NCB; c0 += nbc) {
        const int nb = (NCB - c0 < nbc) ? (NCB - c0) : nbc;
        cvt_w_fp8<<<nb * 64, 256, 0, stream>>>(W, Wh, c0 * 256);
        // 128-col tiles: grid = 8 m-blocks x (2*nb) n-blocks
        gemm_fused<<<nb * 16, 256, 0, stream>>>(Wh, xh, y, ws_se, ws_sl, ws_zy,
                                                c0 * 256, nb * 2);
    }

    finalize_kernel<<<1, 1024, 0, stream>>>(ws_se, ws_sl, ws_zy, y, out, NROWS);
}